// Round 7
// baseline (9716.998 us; speedup 1.0000x reference)
//
#include <hip/hip_runtime.h>
#include <math.h>

// Problem dims
#define TT 2048
#define VV 1024
#define HH 2048
#define SS (VV + HH)        // 3072: row stride of Wf_w / Wb_w

// Geometry: 256 WGs x 512 threads, one WG per CU (forced by ~140KB LDS).
#define NWGD 128            // workgroups per direction
#define BTH  512            // threads per workgroup (8 waves)
#define UPW  16             // hidden units per wg (= rowgroups)
#define KSL  32             // k-slices per row (lanes per rowgroup)
#define KPT  64             // k-elements per thread per row
#define CHR  16             // float4 chunks per row per thread (KPT/4)
#define RCHR 12             // chunks per row in VGPRs (4 gates x 12 x 4 = 192 regs)
#define LCHR 4              // chunks per row in LDS (4 x 4 x 16B x 512 thr = 128KB)

static_assert(NWGD * UPW == HH, "unit coverage");
static_assert(UPW * KSL == BTH, "thread coverage");
static_assert(KSL * KPT == HH, "k coverage");
static_assert(RCHR + LCHR == CHR, "chunk split");

// Flag area (uints), per direction at bar + dir*2048:
//   flag[p] (p<128) at +p*16  (64B stride)
#define BAR_UINTS_PER_DIR 2048

__device__ __forceinline__ float sigmoidf_(float x) {
    return 1.0f / (1.0f + __expf(-x));
}

__global__ __launch_bounds__(BTH, 1)
void lstm_kernel(const float* __restrict__ Wf, const float* __restrict__ bfv,
                 const float* __restrict__ Wb, const float* __restrict__ bbv,
                 const int* __restrict__ cidx,
                 float* __restrict__ hsf, float* __restrict__ hsb,
                 unsigned* __restrict__ bar)
{
    const int wg   = blockIdx.x;
    const int dir  = wg >> 7;            // 0 fwd, 1 bwd
    const int w    = wg & (NWGD - 1);
    const int tid  = threadIdx.x;
    const int rg   = tid >> 5;           // unit_local 0..15
    const int ks   = tid & (KSL - 1);    // k-slice 0..31
    const int unit = w * UPW + rg;

    const float* W    = dir ? Wb : Wf;
    const float* bias = dir ? bbv : bfv;
    float* hs         = dir ? hsb : hsf;
    unsigned* flags   = bar + dir * BAR_UINTS_PER_DIR;   // flag[p] = flags[p*16]

    // This thread's 4 rows = the 4 GATES (i,f,g,o) of `unit`:
    // row_j = j*HH + unit. After the 32-lane butterfly every lane holds all
    // four gate dots, so lane ks==0 applies the cell in-register (no glds).

    // LDS: weights [gate*LCHR + c][tid] float4 (lane-sequential, conflict-free),
    // h padded so slice starts hit distinct bank groups (float4 idx 17*ks).
    __shared__ float4 wl4[4 * LCHR * BTH];                // 128 KB
    __shared__ float4 hl4[(HH + 4 * (HH / 64)) / 4];      // 544 float4 = 8.5 KB

    // ---- one-time: weight slab -> VGPRs + LDS ----
    float4 wr[4][RCHR];
    #pragma unroll
    for (int j = 0; j < 4; ++j) {
        const float* rbase = W + (size_t)(j * HH + unit) * SS + VV + ks * KPT;
        #pragma unroll
        for (int c = 0; c < RCHR; ++c)
            wr[j][c] = *reinterpret_cast<const float4*>(rbase + 4 * c);
        #pragma unroll
        for (int c = 0; c < LCHR; ++c)
            wl4[(j * LCHR + c) * BTH + tid] =
                *reinterpret_cast<const float4*>(rbase + 4 * (RCHR + c));
    }
    const float b_i = bias[0 * HH + unit];
    const float b_f = bias[1 * HH + unit];
    const float b_g = bias[2 * HH + unit];
    const float b_o = bias[3 * HH + unit];
    float creg = 0.0f;                                    // cell state (lane ks==0)

    // prestage h=0 for step 0
    hl4[tid + (tid >> 4)] = make_float4(0.f, 0.f, 0.f, 0.f);
    __syncthreads();

    for (int s = 0; s < TT; ++s) {
        const int t  = dir ? (TT - 1 - s) : s;
        const int xt = cidx[t];
        // one-hot gather for this unit's 4 gate rows (issued early, hidden
        // under the dot; exact fp32; L2/L3-hot after step 1)
        float gx0 = 0.f, gx1 = 0.f, gx2 = 0.f, gx3 = 0.f;
        if (ks == 0) {
            gx0 = W[(size_t)(0 * HH + unit) * SS + xt];
            gx1 = W[(size_t)(1 * HH + unit) * SS + xt];
            gx2 = W[(size_t)(2 * HH + unit) * SS + xt];
            gx3 = W[(size_t)(3 * HH + unit) * SS + xt];
        }

        // ---- recurrent dot: 4 gate rows x 64 k; each h-read feeds 16 FMAs ----
        float a0 = 0.f, a1 = 0.f, a2 = 0.f, a3 = 0.f;
        const int hb = 17 * ks;                           // padded float4 base
        #pragma unroll
        for (int c = 0; c < CHR; ++c) {
            const float4 hv = hl4[hb + c];
            float4 w0, w1, w2, w3;
            if (c < RCHR) {
                w0 = wr[0][c]; w1 = wr[1][c]; w2 = wr[2][c]; w3 = wr[3][c];
            } else {
                w0 = wl4[(0 * LCHR + (c - RCHR)) * BTH + tid];
                w1 = wl4[(1 * LCHR + (c - RCHR)) * BTH + tid];
                w2 = wl4[(2 * LCHR + (c - RCHR)) * BTH + tid];
                w3 = wl4[(3 * LCHR + (c - RCHR)) * BTH + tid];
            }
            a0 = fmaf(w0.x, hv.x, a0); a0 = fmaf(w0.y, hv.y, a0);
            a0 = fmaf(w0.z, hv.z, a0); a0 = fmaf(w0.w, hv.w, a0);
            a1 = fmaf(w1.x, hv.x, a1); a1 = fmaf(w1.y, hv.y, a1);
            a1 = fmaf(w1.z, hv.z, a1); a1 = fmaf(w1.w, hv.w, a1);
            a2 = fmaf(w2.x, hv.x, a2); a2 = fmaf(w2.y, hv.y, a2);
            a2 = fmaf(w2.z, hv.z, a2); a2 = fmaf(w2.w, hv.w, a2);
            a3 = fmaf(w3.x, hv.x, a3); a3 = fmaf(w3.y, hv.y, a3);
            a3 = fmaf(w3.z, hv.z, a3); a3 = fmaf(w3.w, hv.w, a3);
        }
        // butterfly over the 32 k-slices (xor<=16 stays within each 32-half)
        #pragma unroll
        for (int off = 1; off < KSL; off <<= 1) {
            a0 += __shfl_xor(a0, off, 64);
            a1 += __shfl_xor(a1, off, 64);
            a2 += __shfl_xor(a2, off, 64);
            a3 += __shfl_xor(a3, off, 64);
        }

        // ---- LSTM cell in-lane (ks==0), h store agent-coherent ----
        if (ks == 0) {
            const float gi = sigmoidf_(a0 + gx0 + b_i);
            const float gf = sigmoidf_(a1 + gx1 + b_f);
            const float gg = tanhf(a2 + gx2 + b_g);
            const float go = sigmoidf_(a3 + gx3 + b_o);
            creg = gf * creg + gi * gg;
            const float hv = go * tanhf(creg);
            __hip_atomic_store(hs + (size_t)t * HH + unit, hv,
                               __ATOMIC_RELAXED, __HIP_MEMORY_SCOPE_AGENT);
        }
        // drain this wave's h stores to the coherence point
        asm volatile("s_waitcnt vmcnt(0)" ::: "memory");
        __syncthreads();   // A: all 16 h stores at L3; hlds free to overwrite

        if (tid == 0)
            __hip_atomic_store(flags + (size_t)w * 16, (unsigned)(s + 1),
                               __ATOMIC_RELAXED, __HIP_MEMORY_SCOPE_AGENT);

        if (s + 1 < TT) {
            // fused poll+stage: thread p (<128) waits for producer p's flag,
            // then stages p's 16 h floats itself (one 64B line per thread).
            if (tid < NWGD) {
                unsigned* fl = flags + (size_t)tid * 16;
                while (__hip_atomic_load(fl, __ATOMIC_RELAXED,
                                         __HIP_MEMORY_SCOPE_AGENT)
                       < (unsigned)(s + 1)) {
                    __builtin_amdgcn_s_sleep(2);
                }
                asm volatile("" ::: "memory");
                const float* hsrc = hs + (size_t)t * HH + tid * 16;
                #pragma unroll
                for (int q = 0; q < 4; ++q) {
                    float4 hv;
                    hv.x = __hip_atomic_load(hsrc + 4 * q,     __ATOMIC_RELAXED, __HIP_MEMORY_SCOPE_AGENT);
                    hv.y = __hip_atomic_load(hsrc + 4 * q + 1, __ATOMIC_RELAXED, __HIP_MEMORY_SCOPE_AGENT);
                    hv.z = __hip_atomic_load(hsrc + 4 * q + 2, __ATOMIC_RELAXED, __HIP_MEMORY_SCOPE_AGENT);
                    hv.w = __hip_atomic_load(hsrc + 4 * q + 3, __ATOMIC_RELAXED, __HIP_MEMORY_SCOPE_AGENT);
                    const int f4i = tid * 4 + q;
                    hl4[f4i + (f4i >> 4)] = hv;
                }
            }
            __syncthreads();   // B: hlds ready for next dot
        }
    }
}

// out[t,v] = sum_j merged[t,j]*Wo[v,j] + bo[v],  merged = [hf | hb], K = 4096.
__global__ __launch_bounds__(256)
void out_gemm(const float* __restrict__ hsf, const float* __restrict__ hsb,
              const float* __restrict__ Wo, const float* __restrict__ bo,
              float* __restrict__ out)
{
    const int bn = blockIdx.x;
    const int bm = blockIdx.y;
    const int tid = threadIdx.x;
    const int tx = tid & 15, ty = tid >> 4;
    const int t0 = bm * 64, v0 = bn * 64;

    __shared__ float As[32][72];
    __shared__ float Bs[32][72];

    float acc[4][4] = {};

    const int rr = tid >> 2;
    const int kc = tid & 3;

    for (int kb = 0; kb < 2 * HH; kb += 32) {
        {
            const int k = kb + kc * 8;
            const float* asrc = (k < HH) ? (hsf + (size_t)(t0 + rr) * HH + k)
                                         : (hsb + (size_t)(t0 + rr) * HH + (k - HH));
            const float4 a0 = *reinterpret_cast<const float4*>(asrc);
            const float4 a1 = *reinterpret_cast<const float4*>(asrc + 4);
            const int kk = kc * 8;
            As[kk+0][rr]=a0.x; As[kk+1][rr]=a0.y; As[kk+2][rr]=a0.z; As[kk+3][rr]=a0.w;
            As[kk+4][rr]=a1.x; As[kk+5][rr]=a1.y; As[kk+6][rr]=a1.z; As[kk+7][rr]=a1.w;
            const float* bsrc = Wo + (size_t)(v0 + rr) * (2 * HH) + k;
            const float4 b0 = *reinterpret_cast<const float4*>(bsrc);
            const float4 b1 = *reinterpret_cast<const float4*>(bsrc + 4);
            Bs[kk+0][rr]=b0.x; Bs[kk+1][rr]=b0.y; Bs[kk+2][rr]=b0.z; Bs[kk+3][rr]=b0.w;
            Bs[kk+4][rr]=b1.x; Bs[kk+5][rr]=b1.y; Bs[kk+6][rr]=b1.z; Bs[kk+7][rr]=b1.w;
        }
        __syncthreads();
        #pragma unroll 8
        for (int kk = 0; kk < 32; ++kk) {
            const float4 av = *reinterpret_cast<const float4*>(&As[kk][ty * 4]);
            const float4 bv = *reinterpret_cast<const float4*>(&Bs[kk][tx * 4]);
            const float a[4] = {av.x, av.y, av.z, av.w};
            const float b[4] = {bv.x, bv.y, bv.z, bv.w};
            #pragma unroll
            for (int i2 = 0; i2 < 4; ++i2)
                #pragma unroll
                for (int j2 = 0; j2 < 4; ++j2)
                    acc[i2][j2] = fmaf(a[i2], b[j2], acc[i2][j2]);
        }
        __syncthreads();
    }
    #pragma unroll
    for (int i2 = 0; i2 < 4; ++i2) {
        const int t = t0 + ty * 4 + i2;
        #pragma unroll
        for (int j2 = 0; j2 < 4; ++j2) {
            const int v = v0 + tx * 4 + j2;
            out[(size_t)t * VV + v] = acc[i2][j2] + bo[v];
        }
    }
}

extern "C" void kernel_launch(void* const* d_in, const int* in_sizes, int n_in,
                              void* d_out, int out_size, void* d_ws, size_t ws_size,
                              hipStream_t stream)
{
    (void)in_sizes; (void)n_in; (void)out_size; (void)ws_size;

    const float* Wf  = (const float*)d_in[0];
    const float* bfv = (const float*)d_in[1];
    const float* Wb  = (const float*)d_in[2];
    const float* bbv = (const float*)d_in[3];
    const float* Wo  = (const float*)d_in[4];
    const float* bo  = (const float*)d_in[5];
    const int*   cid = (const int*)d_in[6];
    float* out = (float*)d_out;

    unsigned char* ws = (unsigned char*)d_ws;
    unsigned* bar = (unsigned*)ws;                         // 16 KiB flag area
    float* hsf = (float*)(ws + 65536);                     // [T][H] fp32, 16 MiB
    float* hsb = hsf + (size_t)TT * HH;                    // [T][H] fp32, 16 MiB

    (void)hipMemsetAsync(bar, 0, 16384, stream);

    lstm_kernel<<<dim3(2 * NWGD), dim3(BTH), 0, stream>>>(Wf, bfv, Wb, bbv, cid,
                                                          hsf, hsb, bar);
    out_gemm<<<dim3(VV / 64, TT / 64), dim3(256), 0, stream>>>(hsf, hsb, Wo, bo, out);
}